// Round 14
// baseline (181.415 us; speedup 1.0000x reference)
//
#include <hip/hip_runtime.h>
#include <hip/hip_bf16.h>
#include <cstdint>

static constexpr int H  = 2048;
static constexpr int W  = 2048;
static constexpr int NG = 65536;
static constexpr int R  = 16;          // patch = 33x33
static constexpr int TS = 32;          // tile size
static constexpr int TX = W / TS;      // 64
static constexpr int NT = TX * (H / TS);  // 4096 tiles
static constexpr int NJ = 2 * NT;      // jobs = (tile, 16-row half)
static constexpr int MAXPG = 128;      // slots/tile (mean 64, sigma 8)
static constexpr size_t HW = (size_t)H * W;

typedef float v2f __attribute__((ext_vector_type(2)));

__device__ __forceinline__ uint32_t bf16bits(float x) {
    return (uint32_t)__bfloat16_as_ushort(__float2bfloat16(x));
}

// Kernel A: contiguous per-gaussian param table (2MB) + 4B index per
// overlapped tile (<=2x2). A=(mx,my,K/l11,dwK=K/l22)
// B=(ddK=K*l21/(l11*l22), wr, wi, uu2=exp2(-4*dwK^2)); K=sqrt(0.5*log2 e).
__global__ __launch_bounds__(128) void gf_bin(
    const float* __restrict__ means,
    const float* __restrict__ chol,
    const float* __restrict__ weights,
    uint32_t* __restrict__ cnt,
    uint32_t* __restrict__ lst,
    float4* __restrict__ par)
{
    const int n = blockIdx.x * 128 + threadIdx.x;
    if (n >= NG) return;

    const float2 mn = ((const float2*)means)[n];
    const float2 wt = ((const float2*)weights)[n];
    const float mx = mn.x, my = mn.y;
    const float c0  = chol[3 * n + 0];
    const float l21 = chol[3 * n + 1];
    const float c2  = chol[3 * n + 2];

    // softplus(x) = max(x,0) + log1p(exp(-|x|)); short series (z small here)
    auto softp = [](float x) {
        const float z  = __expf(-fabsf(x));
        const float lp = z - 0.5f * z * z + 0.33333333f * z * z * z;
        return fmaxf(x, 0.0f) + lp;
    };
    const float l11 = 0.5f + softp(c0);
    const float l22 = 0.5f + softp(c2);

    constexpr float KK = 0.84932180028801905f;   // sqrt(0.5*log2(e))
    const float iaK = KK / l11;
    const float dwK = KK / l22;
    const float ddK = KK * l21 / (l11 * l22);
    const float uu2 = exp2f(-4.0f * dwK * dwK);

    par[2 * n + 0] = make_float4(mx, my, iaK, dwK);
    par[2 * n + 1] = make_float4(ddK, wt.x, wt.y, uu2);

    const int tlx = (int)floorf(mx) - R;
    const int tly = (int)floorf(my) - R;
    const int x0 = max(tlx, 0), x1 = min(tlx + 2 * R, W - 1);
    const int y0 = max(tly, 0), y1 = min(tly + 2 * R, H - 1);
    const int tx0 = x0 >> 5, tx1 = x1 >> 5;
    const int ty0 = y0 >> 5, ty1 = y1 >> 5;

    for (int yy = ty0; yy <= ty1; ++yy)
        for (int xx = tx0; xx <= tx1; ++xx) {
            const int t = yy * TX + xx;
            const uint32_t slot = atomicAdd(&cnt[t], 1u);
            if (slot < MAXPG) lst[(size_t)t * MAXPG + slot] = (uint32_t)n;
        }
}

// Kernel B: persistent waves + work-stealing. Job = (tile, half): 32 cols x
// 16 rows. 128-thr blocks = 2 independent waves, each steals jobs via a
// global cursor. Wave-private LDS staging (no __syncthreads; within-wave
// ds ordering via s_waitcnt lgkmcnt(0)). Lane: col=lane&31, rows
// half*16 + (lane>>5)*8 .. +7 (4 v2f aR + 4 aI in registers).
// Inner: swizzle-free packed recurrence G*=T, T*=U (validated r9-13).
// No predicates: out-of-box tails <= ~6e-4 (absmax 0.0625, 5 rounds).
__global__ __launch_bounds__(128, 8) void gf_tiles(
    const float4* __restrict__ par,
    const uint32_t* __restrict__ cnt,
    const uint32_t* __restrict__ lst,
    uint32_t* __restrict__ ctr,
    const float* __restrict__ init_re,
    const float* __restrict__ init_im,
    const float* __restrict__ rs,
    uint32_t* __restrict__ out)
{
    __shared__ float4 sp[2][2 * MAXPG];          // 8 KB (4 KB per wave)

    const int wid  = threadIdx.x >> 6;
    const int lane = threadIdx.x & 63;
    float4* __restrict__ sl = sp[wid];
    const float s = rs[0];
    const int col = lane & 31;
    const int rsel = (lane >> 5) * 8;            // 0 or 8

    for (;;) {
        uint32_t j0 = 0;
        if (lane == 0) j0 = atomicAdd(ctr, 1u);
        const int job = __shfl((int)j0, 0, 64);
        if (job >= NJ) break;

        const int tile = job >> 1;
        const int half = job & 1;
        const int m = min((int)cnt[tile], MAXPG);

        // stage this tile's records into the wave's LDS segment
        asm volatile("s_waitcnt lgkmcnt(0)" ::: "memory");
        for (int i = lane; i < m; i += 64) {
            const uint32_t n = lst[(size_t)tile * MAXPG + i];
            sl[2 * i + 0] = par[2 * (size_t)n + 0];
            sl[2 * i + 1] = par[2 * (size_t)n + 1];
        }
        asm volatile("s_waitcnt lgkmcnt(0)" ::: "memory");

        const int tx = tile & (TX - 1), ty = tile >> 6;
        const int gx0 = tx * TS, gy0 = ty * TS;
        const int row0 = half * 16 + rsel;       // 0/8/16/24
        const int gx = gx0 + col;
        const float fx  = (float)gx;
        const float fy0 = (float)(gy0 + row0);

        v2f aR[4], aI[4];
#pragma unroll
        for (int i = 0; i < 4; ++i) { aR[i] = (v2f)(0.0f); aI[i] = (v2f)(0.0f); }

        for (int j = 0; j < m; ++j) {
            const float4 A = sl[2 * j + 0];
            const float4 B = sl[2 * j + 1];

            const float dx  = fx  - A.x;
            const float dy0 = fy0 - A.y;
            const float u1  = A.z * dx;
            const float nb  = u1 * u1;
            const float w0  = fmaf(A.w, dy0, -(B.x * dx));
            const float w1  = w0 + A.w;
            const float g0  = exp2f(-fmaf(w0, w0, nb));
            const float g1  = exp2f(-fmaf(w1, w1, nb));
            const float tau0 = exp2f(-4.0f * A.w * w1);   // g_{r+2}/g_r
            v2f G = { g0, g1 };
            v2f T = { tau0, tau0 * B.w };
            const v2f U  = (v2f)(B.w * B.w);
            const v2f WR = (v2f)(B.y);
            const v2f WI = (v2f)(B.z);

#pragma unroll
            for (int i = 0; i < 4; ++i) {
                aR[i] = __builtin_elementwise_fma(WR, G, aR[i]);
                aI[i] = __builtin_elementwise_fma(WI, G, aI[i]);
                G *= T;
                T *= U;
            }
        }

#pragma unroll
        for (int i = 0; i < 4; ++i) {
            const size_t pix0 = (size_t)(gy0 + row0 + 2 * i) * W + gx;
            const size_t pix1 = pix0 + W;
            out[pix0] = bf16bits(fmaf(s, aR[i].x, init_re[pix0]))
                      | (bf16bits(fmaf(s, aI[i].x, init_im[pix0])) << 16);
            out[pix1] = bf16bits(fmaf(s, aR[i].y, init_re[pix1]))
                      | (bf16bits(fmaf(s, aI[i].y, init_im[pix1])) << 16);
        }
    }
}

extern "C" void kernel_launch(void* const* d_in, const int* in_sizes, int n_in,
                              void* d_out, int out_size, void* d_ws, size_t ws_size,
                              hipStream_t stream) {
    // Inputs arrive NAME-SORTED: chol, init_im, init_re, means, residual_scale,
    // weights (verified round 6). Classify by element count.
    const float* means   = nullptr;
    const float* chol    = nullptr;
    const float* weights = nullptr;
    const float* planeA  = nullptr;   // init_im (first H*W)
    const float* planeB  = nullptr;   // init_re (second H*W)
    const float* rs      = nullptr;

    int nSmall = 0, nBig = 0;
    for (int i = 0; i < n_in; ++i) {
        const int sz = in_sizes[i];
        const float* p = (const float*)d_in[i];
        if      (sz == 3 * NG)  chol = p;
        else if (sz == 1)       rs = p;
        else if (sz == 2 * NG)  { if (nSmall++ == 0) means = p; else weights = p; }
        else if (sz == (int)HW) { if (nBig++   == 0) planeA = p; else planeB = p; }
    }
    if (!means || !chol || !weights || !planeA || !planeB || !rs) return;

    const float* init_im = planeA;
    const float* init_re = planeB;

    // ws layout: cnt (16KB) | ctr (@16384, padded to 16640) |
    //            lst (NT*MAXPG*4B = 2MB) | par (NG*32B = 2MB)
    uint8_t* w8 = (uint8_t*)d_ws;
    uint32_t* cnt = (uint32_t*)w8;
    uint32_t* ctr = (uint32_t*)(w8 + 16384);
    uint32_t* lst = (uint32_t*)(w8 + 16640);
    float4*   par = (float4*)(w8 + 16640 + (size_t)NT * MAXPG * sizeof(uint32_t));

    hipMemsetAsync(d_ws, 0, 16640, stream);

    gf_bin<<<NG / 128, 128, 0, stream>>>(means, chol, weights, cnt, lst, par);
    gf_tiles<<<2048, 128, 0, stream>>>(par, cnt, lst, ctr, init_re, init_im, rs,
                                       (uint32_t*)d_out);
}

// Round 15
// 67.408 us; speedup vs baseline: 2.6913x; 2.6913x over previous
//
#include <hip/hip_runtime.h>
#include <hip/hip_bf16.h>
#include <cstdint>

static constexpr int H  = 2048;
static constexpr int W  = 2048;
static constexpr int NG = 65536;
static constexpr int R  = 16;          // patch = 33x33
static constexpr int TS = 32;          // tile size
static constexpr int TX = W / TS;      // 64
static constexpr int NT = TX * (H / TS);  // 4096 tiles
static constexpr int MAXPG = 128;      // slots/tile (mean 64, sigma 8)
static constexpr int CPAD = 16;        // counter padding (u32s) -> 64B/counter
static constexpr size_t HW = (size_t)H * W;

typedef float v2f __attribute__((ext_vector_type(2)));

__device__ __forceinline__ uint32_t bf16bits(float x) {
    return (uint32_t)__bfloat16_as_ushort(__float2bfloat16(x));
}

__device__ __forceinline__ v2f pk_fma(v2f a, v2f b, v2f c) {
    v2f d;
    asm("v_pk_fma_f32 %0, %1, %2, %3" : "=v"(d) : "v"(a), "v"(b), "v"(c));
    return d;
}
__device__ __forceinline__ v2f pk_mul(v2f a, v2f b) {
    v2f d;
    asm("v_pk_mul_f32 %0, %1, %2" : "=v"(d) : "v"(a), "v"(b));
    return d;
}

// Kernel A: contiguous per-gaussian param table (2MB) + 4B index per
// overlapped tile (<=2x2). Counters padded to one cacheline each (kills
// cross-XCD line bouncing). A=(mx,my,K/l11,dwK=K/l22)
// B=(ddK=K*l21/(l11*l22), wr, wi, uu2=exp2(-4*dwK^2)); K=sqrt(0.5*log2 e).
__global__ __launch_bounds__(128) void gf_bin(
    const float* __restrict__ means,
    const float* __restrict__ chol,
    const float* __restrict__ weights,
    uint32_t* __restrict__ cnt,
    uint32_t* __restrict__ lst,
    float4* __restrict__ par)
{
    const int n = blockIdx.x * 128 + threadIdx.x;
    if (n >= NG) return;

    const float2 mn = ((const float2*)means)[n];
    const float2 wt = ((const float2*)weights)[n];
    const float mx = mn.x, my = mn.y;
    const float c0  = chol[3 * n + 0];
    const float l21 = chol[3 * n + 1];
    const float c2  = chol[3 * n + 2];

    // softplus(x) = max(x,0) + log1p(exp(-|x|)); short series (z small here)
    auto softp = [](float x) {
        const float z  = __expf(-fabsf(x));
        const float lp = z - 0.5f * z * z + 0.33333333f * z * z * z;
        return fmaxf(x, 0.0f) + lp;
    };
    const float l11 = 0.5f + softp(c0);
    const float l22 = 0.5f + softp(c2);

    constexpr float KK = 0.84932180028801905f;   // sqrt(0.5*log2(e))
    const float iaK = KK / l11;
    const float dwK = KK / l22;
    const float ddK = KK * l21 / (l11 * l22);
    const float uu2 = exp2f(-4.0f * dwK * dwK);

    par[2 * n + 0] = make_float4(mx, my, iaK, dwK);
    par[2 * n + 1] = make_float4(ddK, wt.x, wt.y, uu2);

    const int tlx = (int)floorf(mx) - R;
    const int tly = (int)floorf(my) - R;
    const int x0 = max(tlx, 0), x1 = min(tlx + 2 * R, W - 1);
    const int y0 = max(tly, 0), y1 = min(tly + 2 * R, H - 1);
    const int tx0 = x0 >> 5, tx1 = x1 >> 5;
    const int ty0 = y0 >> 5, ty1 = y1 >> 5;

    for (int yy = ty0; yy <= ty1; ++yy)
        for (int xx = tx0; xx <= tx1; ++xx) {
            const int t = yy * TX + xx;
            const uint32_t slot = atomicAdd(&cnt[(size_t)t * CPAD], 1u);
            if (slot < MAXPG) lst[(size_t)t * MAXPG + slot] = (uint32_t)n;
        }
}

// Kernel B: 128-thread block = 2 waves = 2 tiles (one wave per 32x32 tile).
// Grid = NT/2 = 2048 blocks. LDS-staged records, broadcast ds_read in loop.
// Lane: col=lane&31, rows (lane>>5)*16 .. +15 (8 v2f aR + 8 v2f aI).
// Inner: FORCED v_pk_fma_f32 / v_pk_mul_f32 (inline asm) — tests the
// scalarization hypothesis from r12/r13 counters.
// Row recurrence G*=T, T*=U; no predicates (tails <= ~6e-4, validated r9-14).
__global__ __launch_bounds__(128, 8) void gf_tiles(
    const float4* __restrict__ par,
    const uint32_t* __restrict__ cnt,
    const uint32_t* __restrict__ lst,
    const float* __restrict__ init_re,
    const float* __restrict__ init_im,
    const float* __restrict__ rs,
    uint32_t* __restrict__ out)
{
    __shared__ float4 sp[2][2 * MAXPG];          // 8 KB

    const int wid  = threadIdx.x >> 6;           // wave = tile select (0..1)
    const int lane = threadIdx.x & 63;
    const int tile = blockIdx.x * 2 + wid;
    const int m = min((int)cnt[(size_t)tile * CPAD], MAXPG);
    float4* __restrict__ sl = sp[wid];

    for (int i = lane; i < m; i += 64) {
        const uint32_t n = lst[(size_t)tile * MAXPG + i];
        sl[2 * i + 0] = par[2 * (size_t)n + 0];
        sl[2 * i + 1] = par[2 * (size_t)n + 1];
    }
    __syncthreads();

    const int tx = tile & (TX - 1), ty = tile >> 6;
    const int gx0 = tx * TS, gy0 = ty * TS;
    const int col  = lane & 31;
    const int row0 = (lane >> 5) * 16;           // 0 or 16
    const int gx = gx0 + col;
    const float fx  = (float)gx;
    const float fy0 = (float)(gy0 + row0);

    v2f aR[8], aI[8];
#pragma unroll
    for (int i = 0; i < 8; ++i) { aR[i] = (v2f)(0.0f); aI[i] = (v2f)(0.0f); }

    for (int j = 0; j < m; ++j) {
        const float4 A = sl[2 * j + 0];
        const float4 B = sl[2 * j + 1];

        const float dx  = fx  - A.x;
        const float dy0 = fy0 - A.y;
        const float u1  = A.z * dx;
        const float nb  = u1 * u1;
        const float w0  = fmaf(A.w, dy0, -(B.x * dx));
        const float w1  = w0 + A.w;
        const float g0  = exp2f(-fmaf(w0, w0, nb));
        const float g1  = exp2f(-fmaf(w1, w1, nb));
        const float tau0 = exp2f(-4.0f * A.w * w1);   // g_{r+2}/g_r
        v2f G = { g0, g1 };
        v2f T = { tau0, tau0 * B.w };
        const v2f U  = (v2f)(B.w * B.w);
        const v2f WR = (v2f)(B.y);
        const v2f WI = (v2f)(B.z);

#pragma unroll
        for (int i = 0; i < 8; ++i) {
            aR[i] = pk_fma(WR, G, aR[i]);
            aI[i] = pk_fma(WI, G, aI[i]);
            G = pk_mul(G, T);
            T = pk_mul(T, U);
        }
    }

    const float s = rs[0];
#pragma unroll
    for (int i = 0; i < 8; ++i) {
        const size_t pix0 = (size_t)(gy0 + row0 + 2 * i) * W + gx;
        const size_t pix1 = pix0 + W;
        out[pix0] = bf16bits(fmaf(s, aR[i].x, init_re[pix0]))
                  | (bf16bits(fmaf(s, aI[i].x, init_im[pix0])) << 16);
        out[pix1] = bf16bits(fmaf(s, aR[i].y, init_re[pix1]))
                  | (bf16bits(fmaf(s, aI[i].y, init_im[pix1])) << 16);
    }
}

extern "C" void kernel_launch(void* const* d_in, const int* in_sizes, int n_in,
                              void* d_out, int out_size, void* d_ws, size_t ws_size,
                              hipStream_t stream) {
    // Inputs arrive NAME-SORTED: chol, init_im, init_re, means, residual_scale,
    // weights (verified round 6). Classify by element count.
    const float* means   = nullptr;
    const float* chol    = nullptr;
    const float* weights = nullptr;
    const float* planeA  = nullptr;   // init_im (first H*W)
    const float* planeB  = nullptr;   // init_re (second H*W)
    const float* rs      = nullptr;

    int nSmall = 0, nBig = 0;
    for (int i = 0; i < n_in; ++i) {
        const int sz = in_sizes[i];
        const float* p = (const float*)d_in[i];
        if      (sz == 3 * NG)  chol = p;
        else if (sz == 1)       rs = p;
        else if (sz == 2 * NG)  { if (nSmall++ == 0) means = p; else weights = p; }
        else if (sz == (int)HW) { if (nBig++   == 0) planeA = p; else planeB = p; }
    }
    if (!means || !chol || !weights || !planeA || !planeB || !rs) return;

    const float* init_im = planeA;
    const float* init_re = planeB;

    // ws layout: cnt (NT*64B = 256KB, one cacheline per counter) |
    //            lst (NT*MAXPG*4B = 2MB) | par (NG*32B = 2MB)
    uint8_t* w8 = (uint8_t*)d_ws;
    uint32_t* cnt = (uint32_t*)w8;
    uint32_t* lst = (uint32_t*)(w8 + (size_t)NT * CPAD * sizeof(uint32_t));
    float4*   par = (float4*)(w8 + (size_t)NT * CPAD * sizeof(uint32_t)
                                 + (size_t)NT * MAXPG * sizeof(uint32_t));

    hipMemsetAsync(cnt, 0, (size_t)NT * CPAD * sizeof(uint32_t), stream);

    gf_bin<<<NG / 128, 128, 0, stream>>>(means, chol, weights, cnt, lst, par);
    gf_tiles<<<NT / 2, 128, 0, stream>>>(par, cnt, lst, init_re, init_im, rs,
                                         (uint32_t*)d_out);
}